// Round 2
// baseline (1217.159 us; speedup 1.0000x reference)
//
#include <hip/hip_runtime.h>

// ---------------------------------------------------------------------------
// GINEncoder: 2x GINEConv(eps=0, MLP 128->128->128, edge_lin 32->128) + head.
//   1. Build CSR by dst once per call (hist + scan + scatter).
//   2. Per-layer aggregation: one wave per node, edge-embedding weights (32x128)
//      held in registers (64 VGPR/lane), accumulate h = x + sum relu(x_src+emb).
//   3. fp32 register-tiled GEMMs for the MLPs / head (no fp32 MFMA on CDNA4).
// NOTE: edge_index is int64 in the reference but the harness passes integer
// inputs as int32 -> cast to const int*. (Round 1 crash: reading it as int64
// ran 2x past the buffer and produced wild atomics.)
// ---------------------------------------------------------------------------

#define ND 128  // node feature dim (D_IN = D_H = D_OUT = 128)
#define ED 32   // edge feature dim

__global__ __launch_bounds__(256) void zero_kernel(int* __restrict__ p, int n) {
    int i = blockIdx.x * blockDim.x + threadIdx.x;
    if (i < n) p[i] = 0;
}

__global__ __launch_bounds__(256) void hist_kernel(const int* __restrict__ ei,
                                                   int* __restrict__ counts, int E) {
    int i = blockIdx.x * blockDim.x + threadIdx.x;
    if (i < E) atomicAdd(&counts[ei[E + i]], 1);
}

__global__ __launch_bounds__(1024) void scan_kernel(const int* __restrict__ counts,
                                                    int* __restrict__ row_start,
                                                    int* __restrict__ woff, int N) {
    __shared__ int sums[1024];
    int t = threadIdx.x;
    int chunk = (N + 1023) >> 10;
    int lo = min(t * chunk, N);
    int hi = min(lo + chunk, N);
    int s = 0;
    for (int i = lo; i < hi; ++i) s += counts[i];
    sums[t] = s;
    __syncthreads();
    // Hillis-Steele inclusive scan over 1024 partials
    for (int off = 1; off < 1024; off <<= 1) {
        int v = (t >= off) ? sums[t - off] : 0;
        __syncthreads();
        sums[t] += v;
        __syncthreads();
    }
    int pre = (t == 0) ? 0 : sums[t - 1];
    for (int i = lo; i < hi; ++i) {
        row_start[i] = pre;
        woff[i] = pre;
        pre += counts[i];
    }
    if (t == 1023) row_start[N] = sums[1023];
}

__global__ __launch_bounds__(256) void scatter_kernel(const int* __restrict__ ei,
                                                      int* __restrict__ woff,
                                                      int* __restrict__ csr_src,
                                                      int* __restrict__ csr_eid, int E) {
    int i = blockIdx.x * blockDim.x + threadIdx.x;
    if (i < E) {
        int d = ei[E + i];
        int p = atomicAdd(&woff[d], 1);
        csr_src[p] = ei[i];
        csr_eid[p] = i;
    }
}

// One wave per node: h[v] = x[v] + sum_{e: dst=v} relu(x[src_e] + ea_e @ we + be)
// we (32x128) lives in registers: lane handles cols (lane) and (lane+64).
__global__ __launch_bounds__(256) void agg_kernel(
    const float* __restrict__ xin, const float* __restrict__ edge_attr,
    const float* __restrict__ we, const float* __restrict__ be,
    const int* __restrict__ row_start, const int* __restrict__ csr_src,
    const int* __restrict__ csr_eid, float* __restrict__ hout, int N) {
    int lane = threadIdx.x & 63;
    int wave = threadIdx.x >> 6;

    float w0[ED], w1[ED];
#pragma unroll
    for (int k = 0; k < ED; ++k) {
        w0[k] = we[k * ND + lane];
        w1[k] = we[k * ND + 64 + lane];
    }
    float b0 = be[lane];
    float b1 = be[64 + lane];

    for (int v = blockIdx.x * 4 + wave; v < N; v += gridDim.x * 4) {
        float acc0 = xin[(size_t)v * ND + lane];
        float acc1 = xin[(size_t)v * ND + 64 + lane];
        int beg = row_start[v];
        int end = row_start[v + 1];
        for (int i = beg; i < end; ++i) {
            int s = csr_src[i];
            int e = csr_eid[i];
            const float4* ea4 = (const float4*)(edge_attr + (size_t)e * ED);
            float xs0 = xin[(size_t)s * ND + lane];
            float xs1 = xin[(size_t)s * ND + 64 + lane];
            float emb0 = b0, emb1 = b1;
#pragma unroll
            for (int j = 0; j < ED / 4; ++j) {
                float4 a = ea4[j];
                emb0 += a.x * w0[4 * j] + a.y * w0[4 * j + 1] + a.z * w0[4 * j + 2] +
                        a.w * w0[4 * j + 3];
                emb1 += a.x * w1[4 * j] + a.y * w1[4 * j + 1] + a.z * w1[4 * j + 2] +
                        a.w * w1[4 * j + 3];
            }
            float m0 = xs0 + emb0;
            float m1 = xs1 + emb1;
            acc0 += m0 > 0.0f ? m0 : 0.0f;
            acc1 += m1 > 0.0f ? m1 : 0.0f;
        }
        hout[(size_t)v * ND + lane] = acc0;
        hout[(size_t)v * ND + 64 + lane] = acc1;
    }
}

// C[r][c] = maybe_relu( sum_k A[r][k]*W[k][c] + bias[c] ),  A:[N,128] W:[128,128]
// Block: 256 threads, 32 rows x 128 cols tile; thread computes 4 rows x 4 cols.
__global__ __launch_bounds__(256) void mlp_gemm_kernel(
    const float* __restrict__ A, const float* __restrict__ W,
    const float* __restrict__ bias, float* __restrict__ C, int N, int relu_out) {
    __shared__ float As[32 * ND];
    __shared__ float Ws[32 * ND];
    int t = threadIdx.x;
    int row0 = blockIdx.x * 32;
    int cq = t & 31;         // col quad index: cols cq*4 .. cq*4+3
    int rg = (t >> 5) * 4;   // base local row (0,4,...,28)

    // Load A tile (32 rows x 128): 1024 float4, 4 per thread, guarded by N.
    const float4* A4 = (const float4*)(A + (size_t)row0 * ND);
    float4* As4 = (float4*)As;
#pragma unroll
    for (int j = 0; j < 4; ++j) {
        int f = t + 256 * j;          // float4 index; row_local = f >> 5
        int row = row0 + (f >> 5);
        float4 v = make_float4(0.f, 0.f, 0.f, 0.f);
        if (row < N) v = A4[f];
        As4[f] = v;
    }

    float acc[4][4];
#pragma unroll
    for (int r = 0; r < 4; ++r)
#pragma unroll
        for (int c = 0; c < 4; ++c) acc[r][c] = 0.0f;

    float4* Ws4 = (float4*)Ws;
    for (int kc = 0; kc < 4; ++kc) {
        __syncthreads();  // protect Ws from previous iter's readers; publish As on iter 0
        const float4* W4 = (const float4*)(W + (size_t)kc * 32 * ND);
#pragma unroll
        for (int j = 0; j < 4; ++j) Ws4[t + 256 * j] = W4[t + 256 * j];
        __syncthreads();

#pragma unroll
        for (int k4 = 0; k4 < 8; ++k4) {  // 4 k's per step
            float4 a[4];
#pragma unroll
            for (int r = 0; r < 4; ++r) a[r] = As4[(rg + r) * 32 + kc * 8 + k4];
            float4 wv[4];
#pragma unroll
            for (int j = 0; j < 4; ++j) wv[j] = Ws4[(k4 * 4 + j) * 32 + cq];
#pragma unroll
            for (int r = 0; r < 4; ++r) {
                acc[r][0] += a[r].x * wv[0].x + a[r].y * wv[1].x + a[r].z * wv[2].x +
                             a[r].w * wv[3].x;
                acc[r][1] += a[r].x * wv[0].y + a[r].y * wv[1].y + a[r].z * wv[2].y +
                             a[r].w * wv[3].y;
                acc[r][2] += a[r].x * wv[0].z + a[r].y * wv[1].z + a[r].z * wv[2].z +
                             a[r].w * wv[3].z;
                acc[r][3] += a[r].x * wv[0].w + a[r].y * wv[1].w + a[r].z * wv[2].w +
                             a[r].w * wv[3].w;
            }
        }
    }

    float4 bv = ((const float4*)bias)[cq];
#pragma unroll
    for (int r = 0; r < 4; ++r) {
        int row = row0 + rg + r;
        if (row < N) {
            float4 o;
            o.x = acc[r][0] + bv.x;
            o.y = acc[r][1] + bv.y;
            o.z = acc[r][2] + bv.z;
            o.w = acc[r][3] + bv.w;
            if (relu_out) {
                o.x = o.x > 0.f ? o.x : 0.f;
                o.y = o.y > 0.f ? o.y : 0.f;
                o.z = o.z > 0.f ? o.z : 0.f;
                o.w = o.w > 0.f ? o.w : 0.f;
            }
            ((float4*)(C + (size_t)row * ND))[cq] = o;
        }
    }
}

extern "C" void kernel_launch(void* const* d_in, const int* in_sizes, int n_in,
                              void* d_out, int out_size, void* d_ws, size_t ws_size,
                              hipStream_t stream) {
    const float* x = (const float*)d_in[0];
    const int* ei = (const int*)d_in[1];   // int64 in reference -> int32 from harness
    const float* ea = (const float*)d_in[2];
    const float* w1_0 = (const float*)d_in[3];
    const float* b1_0 = (const float*)d_in[4];
    const float* w2_0 = (const float*)d_in[5];
    const float* b2_0 = (const float*)d_in[6];
    const float* we_0 = (const float*)d_in[7];
    const float* be_0 = (const float*)d_in[8];
    const float* w1_1 = (const float*)d_in[9];
    const float* b1_1 = (const float*)d_in[10];
    const float* w2_1 = (const float*)d_in[11];
    const float* b2_1 = (const float*)d_in[12];
    const float* we_1 = (const float*)d_in[13];
    const float* be_1 = (const float*)d_in[14];
    const float* fc1_w = (const float*)d_in[15];
    const float* fc1_b = (const float*)d_in[16];
    const float* fc2_w = (const float*)d_in[17];
    const float* fc2_b = (const float*)d_in[18];

    int N = in_sizes[0] / ND;
    int E = in_sizes[2] / ED;

    float* bufA = (float*)d_ws;
    int* counts = (int*)(bufA + (size_t)N * ND);
    int* row_start = counts + N;
    int* woff = row_start + (N + 1);
    int* csr_src = woff + N;
    int* csr_eid = csr_src + E;
    float* out = (float*)d_out;

    // ---- CSR build (shared by both layers) ----
    zero_kernel<<<(N + 255) / 256, 256, 0, stream>>>(counts, N);
    hist_kernel<<<(E + 255) / 256, 256, 0, stream>>>(ei, counts, E);
    scan_kernel<<<1, 1024, 0, stream>>>(counts, row_start, woff, N);
    scatter_kernel<<<(E + 255) / 256, 256, 0, stream>>>(ei, woff, csr_src, csr_eid, E);

    int aggGrid = (N + 3) / 4;
    int gg = (N + 31) / 32;

    // ---- layer 0 ----
    agg_kernel<<<aggGrid, 256, 0, stream>>>(x, ea, we_0, be_0, row_start, csr_src,
                                            csr_eid, bufA, N);
    mlp_gemm_kernel<<<gg, 256, 0, stream>>>(bufA, w1_0, b1_0, out, N, 1);
    mlp_gemm_kernel<<<gg, 256, 0, stream>>>(out, w2_0, b2_0, bufA, N, 1);  // + layer relu

    // ---- layer 1 ----
    agg_kernel<<<aggGrid, 256, 0, stream>>>(bufA, ea, we_1, be_1, row_start, csr_src,
                                            csr_eid, out, N);
    mlp_gemm_kernel<<<gg, 256, 0, stream>>>(out, w1_1, b1_1, bufA, N, 1);
    mlp_gemm_kernel<<<gg, 256, 0, stream>>>(bufA, w2_1, b2_1, out, N, 1);  // + layer relu

    // ---- head ----
    mlp_gemm_kernel<<<gg, 256, 0, stream>>>(out, fc1_w, fc1_b, bufA, N, 1);
    mlp_gemm_kernel<<<gg, 256, 0, stream>>>(bufA, fc2_w, fc2_b, out, N, 0);
}

// Round 3
// 1099.548 us; speedup vs baseline: 1.1070x; 1.1070x over previous
//
#include <hip/hip_runtime.h>
#include <stdint.h>

// ---------------------------------------------------------------------------
// GINEncoder: 2x GINEConv(eps=0, MLP 128->128->128, edge_lin 32->128) + head.
//   1. CSR by dst (hist + scan + scatter), edges stored as packed int2{src,eid}.
//   2. agg: one wave per node, edge-lin weights (32x128) in registers,
//      SOFTWARE-PIPELINED edge loop: indices prefetched 2 ahead, data (x row
//      halves + full 128B ea row) prefetched 1 ahead -> hides gather latency.
//   3. fp32 GEMMs: 64x128 tile, thread = 8 rows x 4 cols (no fp32 MFMA on CDNA4).
// edge_index is int64 in the reference but harness passes int32.
// ---------------------------------------------------------------------------

#define ND 128  // node feature dim
#define ED 32   // edge feature dim

__global__ __launch_bounds__(256) void zero_kernel(int* __restrict__ p, int n) {
    int i = blockIdx.x * blockDim.x + threadIdx.x;
    if (i < n) p[i] = 0;
}

__global__ __launch_bounds__(256) void hist_kernel(const int* __restrict__ ei,
                                                   int* __restrict__ counts, int E) {
    int i = blockIdx.x * blockDim.x + threadIdx.x;
    if (i < E) atomicAdd(&counts[ei[E + i]], 1);
}

__global__ __launch_bounds__(1024) void scan_kernel(const int* __restrict__ counts,
                                                    int* __restrict__ row_start,
                                                    int* __restrict__ woff, int N) {
    __shared__ int sums[1024];
    int t = threadIdx.x;
    int chunk = (N + 1023) >> 10;
    int lo = min(t * chunk, N);
    int hi = min(lo + chunk, N);
    int s = 0;
    for (int i = lo; i < hi; ++i) s += counts[i];
    sums[t] = s;
    __syncthreads();
    for (int off = 1; off < 1024; off <<= 1) {
        int v = (t >= off) ? sums[t - off] : 0;
        __syncthreads();
        sums[t] += v;
        __syncthreads();
    }
    int pre = (t == 0) ? 0 : sums[t - 1];
    for (int i = lo; i < hi; ++i) {
        row_start[i] = pre;
        woff[i] = pre;
        pre += counts[i];
    }
    if (t == 1023) row_start[N] = sums[1023];
}

__global__ __launch_bounds__(256) void scatter_kernel(const int* __restrict__ ei,
                                                      int* __restrict__ woff,
                                                      int2* __restrict__ pack, int E) {
    int i = blockIdx.x * blockDim.x + threadIdx.x;
    if (i < E) {
        int d = ei[E + i];
        int p = atomicAdd(&woff[d], 1);
        pack[p] = make_int2(ei[i], i);  // {src, eid}
    }
}

// One wave per node: h[v] = x[v] + sum_{e: dst=v} relu(x[src_e] + ea_e @ we + be)
// we (32x128) in registers: lane handles cols lane and lane+64.
// Edge loop software-pipelined: indices 2 ahead, data (x, ea row) 1 ahead.
__global__ __launch_bounds__(256) void agg_kernel(
    const float* __restrict__ xin, const float* __restrict__ edge_attr,
    const float* __restrict__ we, const float* __restrict__ be,
    const int* __restrict__ row_start, const int2* __restrict__ pack,
    float* __restrict__ hout, int N) {
    int lane = threadIdx.x & 63;
    int wave = threadIdx.x >> 6;

    float w0[ED], w1[ED];
#pragma unroll
    for (int k = 0; k < ED; ++k) {
        w0[k] = we[k * ND + lane];
        w1[k] = we[k * ND + 64 + lane];
    }
    float b0 = be[lane];
    float b1 = be[64 + lane];

    int v = blockIdx.x * 4 + wave;
    if (v >= N) return;

    float acc0 = xin[(size_t)v * ND + lane];
    float acc1 = xin[(size_t)v * ND + 64 + lane];
    int beg = row_start[v];
    int end = row_start[v + 1];

    if (end > beg) {
        int2 se_cur = pack[beg];
        int2 se_nxt = pack[(beg + 1 < end) ? beg + 1 : beg];
        float xs0 = xin[(size_t)se_cur.x * ND + lane];
        float xs1 = xin[(size_t)se_cur.x * ND + 64 + lane];
        float4 ea[8];
        {
            const float4* r0 = (const float4*)(edge_attr + (size_t)se_cur.y * ED);
#pragma unroll
            for (int j = 0; j < 8; ++j) ea[j] = r0[j];
        }
        for (int p = beg; p < end; ++p) {
            // indices two ahead
            int pn2 = (p + 2 < end) ? p + 2 : end - 1;
            int2 se_n2 = pack[pn2];
            // data one ahead (se_nxt arrived last iteration)
            float xs0N = xin[(size_t)se_nxt.x * ND + lane];
            float xs1N = xin[(size_t)se_nxt.x * ND + 64 + lane];
            float4 eaN[8];
            const float4* r1 = (const float4*)(edge_attr + (size_t)se_nxt.y * ED);
#pragma unroll
            for (int j = 0; j < 8; ++j) eaN[j] = r1[j];
            // compute current edge
            float emb0 = b0, emb1 = b1;
#pragma unroll
            for (int j = 0; j < 8; ++j) {
                float4 a = ea[j];
                emb0 += a.x * w0[4 * j] + a.y * w0[4 * j + 1] + a.z * w0[4 * j + 2] +
                        a.w * w0[4 * j + 3];
                emb1 += a.x * w1[4 * j] + a.y * w1[4 * j + 1] + a.z * w1[4 * j + 2] +
                        a.w * w1[4 * j + 3];
            }
            float m0 = xs0 + emb0;
            float m1 = xs1 + emb1;
            acc0 += m0 > 0.f ? m0 : 0.f;
            acc1 += m1 > 0.f ? m1 : 0.f;
            // rotate pipeline
#pragma unroll
            for (int j = 0; j < 8; ++j) ea[j] = eaN[j];
            xs0 = xs0N;
            xs1 = xs1N;
            se_nxt = se_n2;
        }
    }
    hout[(size_t)v * ND + lane] = acc0;
    hout[(size_t)v * ND + 64 + lane] = acc1;
}

// C[r][c] = maybe_relu(sum_k A[r][k]*W[k][c] + bias[c]), A:[N,128] W:[128,128]
// Block 256: 64 rows x 128 cols; thread = 8 rows x 4 cols.
__global__ __launch_bounds__(256) void mlp_gemm_kernel(
    const float* __restrict__ A, const float* __restrict__ W,
    const float* __restrict__ bias, float* __restrict__ C, int N, int relu_out) {
    __shared__ float As[64 * ND];   // 32 KB
    __shared__ float Ws[32 * ND];   // 16 KB
    int t = threadIdx.x;
    int row0 = blockIdx.x * 64;
    int cq = t & 31;   // col quad: cols cq*4 .. cq*4+3
    int rg = t >> 5;   // row group: rows rg*8 .. rg*8+7

    const float4* A4 = (const float4*)(A + (size_t)row0 * ND);
    float4* As4 = (float4*)As;
#pragma unroll
    for (int j = 0; j < 8; ++j) {
        int f = t + 256 * j;  // float4 index; row_local = f >> 5
        int row = row0 + (f >> 5);
        float4 v = make_float4(0.f, 0.f, 0.f, 0.f);
        if (row < N) v = A4[f];
        As4[f] = v;
    }

    float acc[8][4];
#pragma unroll
    for (int r = 0; r < 8; ++r)
#pragma unroll
        for (int c = 0; c < 4; ++c) acc[r][c] = 0.0f;

    float4* Ws4 = (float4*)Ws;
    for (int kc = 0; kc < 4; ++kc) {
        __syncthreads();  // publish As (iter 0) / protect Ws readers (iters 1+)
        const float4* W4 = (const float4*)(W + (size_t)kc * 32 * ND);
#pragma unroll
        for (int j = 0; j < 4; ++j) Ws4[t + 256 * j] = W4[t + 256 * j];
        __syncthreads();

#pragma unroll
        for (int k4 = 0; k4 < 8; ++k4) {  // 4 k's per step
            float4 wv[4];
#pragma unroll
            for (int j = 0; j < 4; ++j) wv[j] = Ws4[(k4 * 4 + j) * 32 + cq];
            float4 a[8];
#pragma unroll
            for (int r = 0; r < 8; ++r) a[r] = As4[(rg * 8 + r) * 32 + kc * 8 + k4];
#pragma unroll
            for (int r = 0; r < 8; ++r) {
                acc[r][0] += a[r].x * wv[0].x + a[r].y * wv[1].x + a[r].z * wv[2].x +
                             a[r].w * wv[3].x;
                acc[r][1] += a[r].x * wv[0].y + a[r].y * wv[1].y + a[r].z * wv[2].y +
                             a[r].w * wv[3].y;
                acc[r][2] += a[r].x * wv[0].z + a[r].y * wv[1].z + a[r].z * wv[2].z +
                             a[r].w * wv[3].z;
                acc[r][3] += a[r].x * wv[0].w + a[r].y * wv[1].w + a[r].z * wv[2].w +
                             a[r].w * wv[3].w;
            }
        }
    }

    float4 bv = ((const float4*)bias)[cq];
#pragma unroll
    for (int r = 0; r < 8; ++r) {
        int row = row0 + rg * 8 + r;
        if (row < N) {
            float4 o;
            o.x = acc[r][0] + bv.x;
            o.y = acc[r][1] + bv.y;
            o.z = acc[r][2] + bv.z;
            o.w = acc[r][3] + bv.w;
            if (relu_out) {
                o.x = o.x > 0.f ? o.x : 0.f;
                o.y = o.y > 0.f ? o.y : 0.f;
                o.z = o.z > 0.f ? o.z : 0.f;
                o.w = o.w > 0.f ? o.w : 0.f;
            }
            ((float4*)(C + (size_t)row * ND))[cq] = o;
        }
    }
}

extern "C" void kernel_launch(void* const* d_in, const int* in_sizes, int n_in,
                              void* d_out, int out_size, void* d_ws, size_t ws_size,
                              hipStream_t stream) {
    const float* x = (const float*)d_in[0];
    const int* ei = (const int*)d_in[1];  // int64 in reference -> int32 from harness
    const float* ea = (const float*)d_in[2];
    const float* w1_0 = (const float*)d_in[3];
    const float* b1_0 = (const float*)d_in[4];
    const float* w2_0 = (const float*)d_in[5];
    const float* b2_0 = (const float*)d_in[6];
    const float* we_0 = (const float*)d_in[7];
    const float* be_0 = (const float*)d_in[8];
    const float* w1_1 = (const float*)d_in[9];
    const float* b1_1 = (const float*)d_in[10];
    const float* w2_1 = (const float*)d_in[11];
    const float* b2_1 = (const float*)d_in[12];
    const float* we_1 = (const float*)d_in[13];
    const float* be_1 = (const float*)d_in[14];
    const float* fc1_w = (const float*)d_in[15];
    const float* fc1_b = (const float*)d_in[16];
    const float* fc2_w = (const float*)d_in[17];
    const float* fc2_b = (const float*)d_in[18];

    int N = in_sizes[0] / ND;
    int E = in_sizes[2] / ED;

    float* bufA = (float*)d_ws;
    int* counts = (int*)(bufA + (size_t)N * ND);
    int* row_start = counts + N;
    int* woff = row_start + (N + 1);
    int2* pack = (int2*)((((uintptr_t)(woff + N)) + 7) & ~(uintptr_t)7);
    float* out = (float*)d_out;

    // ---- CSR build (shared by both layers) ----
    zero_kernel<<<(N + 255) / 256, 256, 0, stream>>>(counts, N);
    hist_kernel<<<(E + 255) / 256, 256, 0, stream>>>(ei, counts, E);
    scan_kernel<<<1, 1024, 0, stream>>>(counts, row_start, woff, N);
    scatter_kernel<<<(E + 255) / 256, 256, 0, stream>>>(ei, woff, pack, E);

    int aggGrid = (N + 3) / 4;
    int gg = (N + 63) / 64;

    // ---- layer 0 ----
    agg_kernel<<<aggGrid, 256, 0, stream>>>(x, ea, we_0, be_0, row_start, pack, bufA, N);
    mlp_gemm_kernel<<<gg, 256, 0, stream>>>(bufA, w1_0, b1_0, out, N, 1);
    mlp_gemm_kernel<<<gg, 256, 0, stream>>>(out, w2_0, b2_0, bufA, N, 1);  // + layer relu

    // ---- layer 1 ----
    agg_kernel<<<aggGrid, 256, 0, stream>>>(bufA, ea, we_1, be_1, row_start, pack, out, N);
    mlp_gemm_kernel<<<gg, 256, 0, stream>>>(out, w1_1, b1_1, bufA, N, 1);
    mlp_gemm_kernel<<<gg, 256, 0, stream>>>(bufA, w2_1, b2_1, out, N, 1);  // + layer relu

    // ---- head ----
    mlp_gemm_kernel<<<gg, 256, 0, stream>>>(out, fc1_w, fc1_b, bufA, N, 1);
    mlp_gemm_kernel<<<gg, 256, 0, stream>>>(bufA, fc2_w, fc2_b, out, N, 0);
}

// Round 4
// 867.023 us; speedup vs baseline: 1.4038x; 1.2682x over previous
//
#include <hip/hip_runtime.h>
#include <stdint.h>

// ---------------------------------------------------------------------------
// GINEncoder: 2x GINEConv(eps=0, MLP 128->128->128, edge_lin 32->128) + head.
//   1. CSR by dst (hist + scan + scatter), edges packed int4{src, eid, dst, 0}.
//   2. agg: EDGE-CENTRIC persistent waves. 8192 waves, each owns ~74 contiguous
//      CSR edges -> continuous software pipeline (idx 2 ahead, data 1 ahead),
//      no per-node drain, no block churn. Accumulator flushed on dst-change via
//      fp32 atomicAdd; hout pre-initialized to x by a copy kernel.
//   3. GEMMs via bf16x3 MFMA (Ahi*Bhi + Alo*Bhi + Ahi*Blo, fp32 acc): W split
//      once per call into B-fragment-ordered bf16 hi/lo; A split in-kernel.
//      Wave = 48 rows x 128 cols, no LDS, no barriers.
// edge_index is int64 in the reference but harness passes int32.
// ---------------------------------------------------------------------------

#define ND 128
#define ED 32

typedef __attribute__((ext_vector_type(8))) short short8;
typedef __attribute__((ext_vector_type(4))) float f32x4;

__device__ inline unsigned short bf16_hi(float f) {
    union { float f; unsigned u; } v;
    v.f = f;
    return (unsigned short)(v.u >> 16);  // truncation; residual captured by lo
}
__device__ inline float bf16_f(unsigned short h) {
    union { unsigned u; float f; } v;
    v.u = ((unsigned)h) << 16;
    return v.f;
}

__global__ __launch_bounds__(256) void zero_kernel(int* __restrict__ p, int n) {
    int i = blockIdx.x * blockDim.x + threadIdx.x;
    if (i < n) p[i] = 0;
}

__global__ __launch_bounds__(256) void copy4_kernel(float4* __restrict__ dst,
                                                    const float4* __restrict__ src,
                                                    int n4) {
    for (int i = blockIdx.x * blockDim.x + threadIdx.x; i < n4;
         i += gridDim.x * blockDim.x)
        dst[i] = src[i];
}

__global__ __launch_bounds__(256) void hist_kernel(const int* __restrict__ ei,
                                                   int* __restrict__ counts, int E) {
    int i = blockIdx.x * blockDim.x + threadIdx.x;
    if (i < E) atomicAdd(&counts[ei[E + i]], 1);
}

__global__ __launch_bounds__(1024) void scan_kernel(const int* __restrict__ counts,
                                                    int* __restrict__ woff, int N) {
    __shared__ int sums[1024];
    int t = threadIdx.x;
    int chunk = (N + 1023) >> 10;
    int lo = min(t * chunk, N);
    int hi = min(lo + chunk, N);
    int s = 0;
    for (int i = lo; i < hi; ++i) s += counts[i];
    sums[t] = s;
    __syncthreads();
    for (int off = 1; off < 1024; off <<= 1) {
        int v = (t >= off) ? sums[t - off] : 0;
        __syncthreads();
        sums[t] += v;
        __syncthreads();
    }
    int pre = (t == 0) ? 0 : sums[t - 1];
    for (int i = lo; i < hi; ++i) {
        woff[i] = pre;
        pre += counts[i];
    }
}

__global__ __launch_bounds__(256) void scatter_kernel(const int* __restrict__ ei,
                                                      int* __restrict__ woff,
                                                      int4* __restrict__ pack, int E) {
    int i = blockIdx.x * blockDim.x + threadIdx.x;
    if (i < E) {
        int d = ei[E + i];
        int p = atomicAdd(&woff[d], 1);
        pack[p] = make_int4(ei[i], i, d, 0);  // {src, eid, dst, pad}
    }
}

// Split 6 weight matrices [128,128] into bf16 hi/lo, laid out in MFMA B-fragment
// order: chunk c = nt*4+ks (nt: 16-col tile, ks: 32-k step); lane l holds
// B[k = ks*32 + (l>>4)*8 + j][n = nt*16 + (l&15)], j=0..7, contiguous 16B.
__global__ __launch_bounds__(256) void wprep_kernel(
    const float* __restrict__ w0, const float* __restrict__ w1,
    const float* __restrict__ w2, const float* __restrict__ w3,
    const float* __restrict__ w4, const float* __restrict__ w5,
    unsigned short* __restrict__ hi, unsigned short* __restrict__ lo) {
    int t = blockIdx.x * blockDim.x + threadIdx.x;  // 0..2047
    const float* W;
    switch (blockIdx.y) {
        case 0: W = w0; break;
        case 1: W = w1; break;
        case 2: W = w2; break;
        case 3: W = w3; break;
        case 4: W = w4; break;
        default: W = w5; break;
    }
    unsigned short* dh = hi + (size_t)blockIdx.y * 16384;
    unsigned short* dl = lo + (size_t)blockIdx.y * 16384;
    int c = t >> 6, l = t & 63;
    int nt = c >> 2, ks = c & 3;
    int n = nt * 16 + (l & 15);
    int kb = ks * 32 + ((l >> 4) << 3);
#pragma unroll
    for (int j = 0; j < 8; ++j) {
        float f = W[(size_t)(kb + j) * ND + n];
        unsigned short h = bf16_hi(f);
        dh[((size_t)c * 64 + l) * 8 + j] = h;
        dl[((size_t)c * 64 + l) * 8 + j] = bf16_hi(f - bf16_f(h));
    }
}

// Edge-centric aggregation: hout (pre-init to x) += sum relu(x[src] + ea@we+be)
// grouped by dst. Wave owns contiguous CSR range; dst is wave-uniform per edge.
__global__ __launch_bounds__(256) void agg_edges(
    const float* __restrict__ xin, const float* __restrict__ edge_attr,
    const float* __restrict__ we, const float* __restrict__ be,
    const int4* __restrict__ pack, float* __restrict__ hout, int E, int epw) {
    int lane = threadIdx.x & 63;
    int gw = (blockIdx.x * blockDim.x + threadIdx.x) >> 6;
    int beg = gw * epw;
    if (beg >= E) return;
    int end = min(beg + epw, E);

    float w0[ED], w1[ED];
#pragma unroll
    for (int k = 0; k < ED; ++k) {
        w0[k] = we[k * ND + lane];
        w1[k] = we[k * ND + 64 + lane];
    }
    float b0 = be[lane];
    float b1 = be[64 + lane];

    int4 cur = pack[beg];
    int4 nxt = (beg + 1 < end) ? pack[beg + 1] : cur;
    float xs0 = xin[(size_t)cur.x * ND + lane];
    float xs1 = xin[(size_t)cur.x * ND + 64 + lane];
    float4 ea[8];
    {
        const float4* r = (const float4*)(edge_attr + (size_t)cur.y * ED);
#pragma unroll
        for (int j = 0; j < 8; ++j) ea[j] = r[j];
    }
    int cdst = cur.z;
    float acc0 = 0.f, acc1 = 0.f;

    for (int p = beg; p < end; ++p) {
        int pn2 = (p + 2 < end) ? p + 2 : end - 1;
        int4 n2 = pack[pn2];
        float xs0N = xin[(size_t)nxt.x * ND + lane];
        float xs1N = xin[(size_t)nxt.x * ND + 64 + lane];
        float4 eaN[8];
        const float4* r = (const float4*)(edge_attr + (size_t)nxt.y * ED);
#pragma unroll
        for (int j = 0; j < 8; ++j) eaN[j] = r[j];

        if (cur.z != cdst) {  // wave-uniform branch (dst same across lanes)
            atomicAdd(&hout[(size_t)cdst * ND + lane], acc0);
            atomicAdd(&hout[(size_t)cdst * ND + 64 + lane], acc1);
            acc0 = acc1 = 0.f;
            cdst = cur.z;
        }

        float emb0 = b0, emb1 = b1;
#pragma unroll
        for (int j = 0; j < 8; ++j) {
            float4 a = ea[j];
            emb0 += a.x * w0[4 * j] + a.y * w0[4 * j + 1] + a.z * w0[4 * j + 2] +
                    a.w * w0[4 * j + 3];
            emb1 += a.x * w1[4 * j] + a.y * w1[4 * j + 1] + a.z * w1[4 * j + 2] +
                    a.w * w1[4 * j + 3];
        }
        float m0 = xs0 + emb0;
        float m1 = xs1 + emb1;
        acc0 += m0 > 0.f ? m0 : 0.f;
        acc1 += m1 > 0.f ? m1 : 0.f;

#pragma unroll
        for (int j = 0; j < 8; ++j) ea[j] = eaN[j];
        xs0 = xs0N;
        xs1 = xs1N;
        cur = nxt;
        nxt = n2;
    }
    atomicAdd(&hout[(size_t)cdst * ND + lane], acc0);
    atomicAdd(&hout[(size_t)cdst * ND + 64 + lane], acc1);
}

// C[N,128] = maybe_relu(A[N,128] @ W[128,128] + bias) via bf16x3 MFMA.
// Wave = 48 rows (3 m-tiles of 16); A split to bf16 hi/lo in registers;
// B-fragments (hi/lo) streamed from prepped global buffers (L2-hot).
__global__ __launch_bounds__(256) void gemm_mfma(
    const float* __restrict__ A, const unsigned short* __restrict__ wfh,
    const unsigned short* __restrict__ wfl, const float* __restrict__ bias,
    float* __restrict__ C, int N, int relu_out) {
    int lane = threadIdx.x & 63;
    int wave = threadIdx.x >> 6;
    int gw = blockIdx.x * 4 + wave;
    int m0 = gw * 48;
    if (m0 >= N) return;
    int mrow = lane & 15;
    int quad = lane >> 4;

    short8 ahi[3][4], alo[3][4];
#pragma unroll
    for (int mt = 0; mt < 3; ++mt) {
#pragma unroll
        for (int ks = 0; ks < 4; ++ks) {
            int row = m0 + mt * 16 + mrow;
            float f[8];
            if (row < N) {
                const float4* p = (const float4*)(A + (size_t)row * ND) + ks * 8 + quad * 2;
                float4 a0 = p[0], a1 = p[1];
                f[0] = a0.x; f[1] = a0.y; f[2] = a0.z; f[3] = a0.w;
                f[4] = a1.x; f[5] = a1.y; f[6] = a1.z; f[7] = a1.w;
            } else {
#pragma unroll
                for (int j = 0; j < 8; ++j) f[j] = 0.f;
            }
            short8 h, l;
#pragma unroll
            for (int j = 0; j < 8; ++j) {
                unsigned short hh = bf16_hi(f[j]);
                h[j] = (short)hh;
                l[j] = (short)bf16_hi(f[j] - bf16_f(hh));
            }
            ahi[mt][ks] = h;
            alo[mt][ks] = l;
        }
    }

#pragma unroll
    for (int nt = 0; nt < 8; ++nt) {
        f32x4 acc[3];
#pragma unroll
        for (int mt = 0; mt < 3; ++mt) acc[mt] = {0.f, 0.f, 0.f, 0.f};
#pragma unroll
        for (int ks = 0; ks < 4; ++ks) {
            size_t off = ((size_t)(nt * 4 + ks) * 64 + lane) * 8;
            short8 bh = *(const short8*)(wfh + off);
            short8 bl = *(const short8*)(wfl + off);
#pragma unroll
            for (int mt = 0; mt < 3; ++mt) {
                acc[mt] = __builtin_amdgcn_mfma_f32_16x16x32_bf16(ahi[mt][ks], bh, acc[mt], 0, 0, 0);
                acc[mt] = __builtin_amdgcn_mfma_f32_16x16x32_bf16(alo[mt][ks], bh, acc[mt], 0, 0, 0);
                acc[mt] = __builtin_amdgcn_mfma_f32_16x16x32_bf16(ahi[mt][ks], bl, acc[mt], 0, 0, 0);
            }
        }
        float bv = bias[nt * 16 + mrow];
#pragma unroll
        for (int mt = 0; mt < 3; ++mt) {
#pragma unroll
            for (int r = 0; r < 4; ++r) {
                int row = m0 + mt * 16 + quad * 4 + r;  // C/D: col=lane&15, row=quad*4+reg
                if (row < N) {
                    float o = acc[mt][r] + bv;
                    if (relu_out) o = o > 0.f ? o : 0.f;
                    C[(size_t)row * ND + nt * 16 + mrow] = o;
                }
            }
        }
    }
}

extern "C" void kernel_launch(void* const* d_in, const int* in_sizes, int n_in,
                              void* d_out, int out_size, void* d_ws, size_t ws_size,
                              hipStream_t stream) {
    const float* x = (const float*)d_in[0];
    const int* ei = (const int*)d_in[1];  // int64 in reference -> int32 from harness
    const float* ea = (const float*)d_in[2];
    const float* w1_0 = (const float*)d_in[3];
    const float* b1_0 = (const float*)d_in[4];
    const float* w2_0 = (const float*)d_in[5];
    const float* b2_0 = (const float*)d_in[6];
    const float* we_0 = (const float*)d_in[7];
    const float* be_0 = (const float*)d_in[8];
    const float* w1_1 = (const float*)d_in[9];
    const float* b1_1 = (const float*)d_in[10];
    const float* w2_1 = (const float*)d_in[11];
    const float* b2_1 = (const float*)d_in[12];
    const float* we_1 = (const float*)d_in[13];
    const float* be_1 = (const float*)d_in[14];
    const float* fc1_w = (const float*)d_in[15];
    const float* fc1_b = (const float*)d_in[16];
    const float* fc2_w = (const float*)d_in[17];
    const float* fc2_b = (const float*)d_in[18];

    int N = in_sizes[0] / ND;
    int E = in_sizes[2] / ED;

    float* bufA = (float*)d_ws;
    int* counts = (int*)(bufA + (size_t)N * ND);
    int* woff = counts + N;
    int4* pack = (int4*)((((uintptr_t)(woff + N)) + 15) & ~(uintptr_t)15);
    unsigned short* wfh = (unsigned short*)(pack + E);
    unsigned short* wfl = wfh + 6 * 16384;
    float* out = (float*)d_out;

    // ---- CSR build + weight prep ----
    zero_kernel<<<(N + 255) / 256, 256, 0, stream>>>(counts, N);
    hist_kernel<<<(E + 255) / 256, 256, 0, stream>>>(ei, counts, E);
    scan_kernel<<<1, 1024, 0, stream>>>(counts, woff, N);
    scatter_kernel<<<(E + 255) / 256, 256, 0, stream>>>(ei, woff, pack, E);
    wprep_kernel<<<dim3(8, 6), 256, 0, stream>>>(w1_0, w2_0, w1_1, w2_1, fc1_w, fc2_w,
                                                 wfh, wfl);

    const int NWAVES = 8192;  // 2048 blocks x 4 waves, fully resident
    int epw = (E + NWAVES - 1) / NWAVES;
    int n4 = N * ND / 4;
    int gg = (((N + 47) / 48) + 3) / 4;  // gemm blocks (4 waves x 48 rows)

    // ---- layer 0 ----
    copy4_kernel<<<2048, 256, 0, stream>>>((float4*)bufA, (const float4*)x, n4);
    agg_edges<<<NWAVES / 4, 256, 0, stream>>>(x, ea, we_0, be_0, pack, bufA, E, epw);
    gemm_mfma<<<gg, 256, 0, stream>>>(bufA, wfh + 0 * 16384, wfl + 0 * 16384, b1_0, out, N, 1);
    gemm_mfma<<<gg, 256, 0, stream>>>(out, wfh + 1 * 16384, wfl + 1 * 16384, b2_0, bufA, N, 1);

    // ---- layer 1 ----
    copy4_kernel<<<2048, 256, 0, stream>>>((float4*)out, (const float4*)bufA, n4);
    agg_edges<<<NWAVES / 4, 256, 0, stream>>>(bufA, ea, we_1, be_1, pack, out, E, epw);
    gemm_mfma<<<gg, 256, 0, stream>>>(out, wfh + 2 * 16384, wfl + 2 * 16384, b1_1, bufA, N, 1);
    gemm_mfma<<<gg, 256, 0, stream>>>(bufA, wfh + 3 * 16384, wfl + 3 * 16384, b2_1, out, N, 1);

    // ---- head ----
    gemm_mfma<<<gg, 256, 0, stream>>>(out, wfh + 4 * 16384, wfl + 4 * 16384, fc1_b, bufA, N, 1);
    gemm_mfma<<<gg, 256, 0, stream>>>(bufA, wfh + 5 * 16384, wfl + 5 * 16384, fc2_b, out, N, 0);
}

// Round 5
// 666.465 us; speedup vs baseline: 1.8263x; 1.3009x over previous
//
#include <hip/hip_runtime.h>
#include <stdint.h>

// ---------------------------------------------------------------------------
// GINEncoder: 2x GINEConv(eps=0, MLP 128->128->128, edge_lin 32->128) + head.
//   1. CSR by dst (hist + scan + scatter), edges packed int4{src, eid, dst, 0}.
//   2. agg_mfma: NODE-CENTRIC MFMA. Wave per node; 16 edges/chunk = one
//      16x16x32 bf16 A-fragment (M=edges, K=ED=32). emb = ea @ we via MFMA
//      (A split hi/lo = exact; we bf16-hi, err ~1e-3). C-layout rows=edges ->
//      gather x[src] per quad, relu, masked accumulate; shuffle-reduce over
//      quads; store h = x[v] + sum directly (no atomics, no init copy).
//   3. GEMMs via bf16x3 MFMA, 16-row waves (3125 waves -> 3 blocks/CU).
// edge_index is int64 in the reference but harness passes int32.
// ---------------------------------------------------------------------------

#define ND 128
#define ED 32

typedef __attribute__((ext_vector_type(8))) short short8;
typedef __attribute__((ext_vector_type(4))) float f32x4;

__device__ inline unsigned short bf16_hi(float f) {
    union { float f; unsigned u; } v;
    v.f = f;
    return (unsigned short)(v.u >> 16);  // truncation; residual captured by lo
}
__device__ inline float bf16_f(unsigned short h) {
    union { unsigned u; float f; } v;
    v.u = ((unsigned)h) << 16;
    return v.f;
}

__global__ __launch_bounds__(256) void zero_kernel(int* __restrict__ p, int n) {
    int i = blockIdx.x * blockDim.x + threadIdx.x;
    if (i < n) p[i] = 0;
}

__global__ __launch_bounds__(256) void hist_kernel(const int* __restrict__ ei,
                                                   int* __restrict__ counts, int E) {
    int i = blockIdx.x * blockDim.x + threadIdx.x;
    if (i < E) atomicAdd(&counts[ei[E + i]], 1);
}

__global__ __launch_bounds__(1024) void scan_kernel(const int* __restrict__ counts,
                                                    int* __restrict__ row_start,
                                                    int* __restrict__ woff, int N) {
    __shared__ int sums[1024];
    int t = threadIdx.x;
    int chunk = (N + 1023) >> 10;
    int lo = min(t * chunk, N);
    int hi = min(lo + chunk, N);
    int s = 0;
    for (int i = lo; i < hi; ++i) s += counts[i];
    sums[t] = s;
    __syncthreads();
    for (int off = 1; off < 1024; off <<= 1) {
        int v = (t >= off) ? sums[t - off] : 0;
        __syncthreads();
        sums[t] += v;
        __syncthreads();
    }
    int pre = (t == 0) ? 0 : sums[t - 1];
    for (int i = lo; i < hi; ++i) {
        row_start[i] = pre;
        woff[i] = pre;
        pre += counts[i];
    }
    if (t == 1023) row_start[N] = sums[1023];
}

__global__ __launch_bounds__(256) void scatter_kernel(const int* __restrict__ ei,
                                                      int* __restrict__ woff,
                                                      int4* __restrict__ pack, int E) {
    int i = blockIdx.x * blockDim.x + threadIdx.x;
    if (i < E) {
        int d = ei[E + i];
        int p = atomicAdd(&woff[d], 1);
        pack[p] = make_int4(ei[i], i, d, 0);  // {src, eid, dst, pad}
    }
}

// Split 6 weight matrices [128,128] into bf16 hi/lo, MFMA B-fragment order:
// chunk c = nt*4+ks; lane l holds B[k=ks*32+(l>>4)*8+j][n=nt*16+(l&15)], j=0..7.
__global__ __launch_bounds__(256) void wprep_kernel(
    const float* __restrict__ w0, const float* __restrict__ w1,
    const float* __restrict__ w2, const float* __restrict__ w3,
    const float* __restrict__ w4, const float* __restrict__ w5,
    unsigned short* __restrict__ hi, unsigned short* __restrict__ lo) {
    int t = blockIdx.x * blockDim.x + threadIdx.x;  // 0..2047
    const float* W;
    switch (blockIdx.y) {
        case 0: W = w0; break;
        case 1: W = w1; break;
        case 2: W = w2; break;
        case 3: W = w3; break;
        case 4: W = w4; break;
        default: W = w5; break;
    }
    unsigned short* dh = hi + (size_t)blockIdx.y * 16384;
    unsigned short* dl = lo + (size_t)blockIdx.y * 16384;
    int c = t >> 6, l = t & 63;
    int nt = c >> 2, ks = c & 3;
    int n = nt * 16 + (l & 15);
    int kb = ks * 32 + ((l >> 4) << 3);
#pragma unroll
    for (int j = 0; j < 8; ++j) {
        float f = W[(size_t)(kb + j) * ND + n];
        unsigned short h = bf16_hi(f);
        dh[((size_t)c * 64 + l) * 8 + j] = h;
        dl[((size_t)c * 64 + l) * 8 + j] = bf16_hi(f - bf16_f(h));
    }
}

// Prep we [32,128] (2 matrices) into bf16-hi B-fragments: chunk = nt (8);
// lane l holds we[k=(l>>4)*8+j][n=nt*16+(l&15)].
__global__ __launch_bounds__(256) void wprep_we(const float* __restrict__ w0,
                                                const float* __restrict__ w1,
                                                unsigned short* __restrict__ hi) {
    int t = threadIdx.x;
    int c = (blockIdx.x << 2) + (t >> 6);  // nt 0..7
    int l = t & 63;
    const float* W = blockIdx.y ? w1 : w0;
    unsigned short* dh = hi + (size_t)blockIdx.y * 4096;
    int n = c * 16 + (l & 15);
    int kb = (l >> 4) << 3;
#pragma unroll
    for (int j = 0; j < 8; ++j)
        dh[((size_t)c * 64 + l) * 8 + j] = bf16_hi(W[(size_t)(kb + j) * ND + n]);
}

// Node-centric MFMA aggregation.
// h[v] = x[v] + sum_{e: dst=v} relu(x[src_e] + ea_e @ we + be)
__global__ __launch_bounds__(256) void agg_mfma(
    const float* __restrict__ xin, const float* __restrict__ edge_attr,
    const unsigned short* __restrict__ bfh, const float* __restrict__ be,
    const int* __restrict__ row_start, const int4* __restrict__ pack,
    float* __restrict__ hout, int N, int NW) {
    int lane = threadIdx.x & 63;
    int gw = (blockIdx.x * blockDim.x + threadIdx.x) >> 6;
    int m = lane & 15;
    int quad = lane >> 4;

    // we fragments (bf16-hi), held in registers for the whole kernel
    short8 bh[8];
#pragma unroll
    for (int nt = 0; nt < 8; ++nt)
        bh[nt] = *(const short8*)(bfh + ((size_t)nt * 64 + lane) * 8);
    float ber[8];
#pragma unroll
    for (int nt = 0; nt < 8; ++nt) ber[nt] = be[nt * 16 + m];

    for (int v = gw; v < N; v += NW) {
        int beg = row_start[v];
        int end = row_start[v + 1];
        float part[8];
#pragma unroll
        for (int nt = 0; nt < 8; ++nt) part[nt] = 0.f;

        for (int base = beg; base < end; base += 16) {
            int rem = end - base;  // >= 1
            int mm = m < rem ? m : rem - 1;
            int4 pk = pack[base + mm];
            // A fragment: ea[eid][quad*8 .. +7], split hi/lo (exact)
            const float4* ar = (const float4*)(edge_attr + (size_t)pk.y * ED + quad * 8);
            float4 a0 = ar[0], a1 = ar[1];
            float af[8] = {a0.x, a0.y, a0.z, a0.w, a1.x, a1.y, a1.z, a1.w};
            short8 ah, al;
#pragma unroll
            for (int j = 0; j < 8; ++j) {
                unsigned short h = bf16_hi(af[j]);
                ah[j] = (short)h;
                al[j] = (short)bf16_hi(af[j] - bf16_f(h));
            }
            // src indices for my quad's 4 C-rows (edges quad*4+r), from lanes 0..15
            int s0 = __shfl(pk.x, quad * 4 + 0, 64);
            int s1 = __shfl(pk.x, quad * 4 + 1, 64);
            int s2 = __shfl(pk.x, quad * 4 + 2, 64);
            int s3 = __shfl(pk.x, quad * 4 + 3, 64);

            f32x4 acc[8];
#pragma unroll
            for (int nt = 0; nt < 8; ++nt) {
                f32x4 a = {0.f, 0.f, 0.f, 0.f};
                a = __builtin_amdgcn_mfma_f32_16x16x32_bf16(ah, bh[nt], a, 0, 0, 0);
                a = __builtin_amdgcn_mfma_f32_16x16x32_bf16(al, bh[nt], a, 0, 0, 0);
                acc[nt] = a;
            }
#pragma unroll
            for (int r = 0; r < 4; ++r) {
                int sr = (r == 0) ? s0 : (r == 1) ? s1 : (r == 2) ? s2 : s3;
                const float* xr = xin + (size_t)sr * ND + m;
                float vm = (quad * 4 + r) < rem ? 1.f : 0.f;
#pragma unroll
                for (int nt = 0; nt < 8; ++nt) {
                    float msg = xr[nt * 16] + acc[nt][r] + ber[nt];
                    msg = msg > 0.f ? msg : 0.f;
                    part[nt] = fmaf(msg, vm, part[nt]);
                }
            }
        }
        // reduce over quads (cols live in lanes m, m+16, m+32, m+48)
#pragma unroll
        for (int nt = 0; nt < 8; ++nt) {
            float p = part[nt];
            p += __shfl_xor(p, 16, 64);
            p += __shfl_xor(p, 32, 64);
            part[nt] = p;
        }
        // quad q writes cols of tiles 2q, 2q+1
        float o0 = quad == 0 ? part[0] : quad == 1 ? part[2] : quad == 2 ? part[4] : part[6];
        float o1 = quad == 0 ? part[1] : quad == 1 ? part[3] : quad == 2 ? part[5] : part[7];
        int col0 = quad * 32 + m;
        int col1 = col0 + 16;
        hout[(size_t)v * ND + col0] = xin[(size_t)v * ND + col0] + o0;
        hout[(size_t)v * ND + col1] = xin[(size_t)v * ND + col1] + o1;
    }
}

// C[N,128] = maybe_relu(A[N,128] @ W[128,128] + bias) via bf16x3 MFMA.
// Wave = 16 rows; A split hi/lo in registers; B-fragments from prepped buffers.
__global__ __launch_bounds__(256) void gemm_mfma(
    const float* __restrict__ A, const unsigned short* __restrict__ wfh,
    const unsigned short* __restrict__ wfl, const float* __restrict__ bias,
    float* __restrict__ C, int N, int relu_out) {
    int lane = threadIdx.x & 63;
    int wave = threadIdx.x >> 6;
    int gw = blockIdx.x * 4 + wave;
    int m0 = gw * 16;
    if (m0 >= N) return;
    int m = lane & 15;
    int quad = lane >> 4;
    int row = m0 + m;
    bool rok = row < N;

    short8 ah[4], al[4];
#pragma unroll
    for (int ks = 0; ks < 4; ++ks) {
        float f[8];
        if (rok) {
            const float4* p = (const float4*)(A + (size_t)row * ND + ks * 32 + quad * 8);
            float4 a0 = p[0], a1 = p[1];
            f[0] = a0.x; f[1] = a0.y; f[2] = a0.z; f[3] = a0.w;
            f[4] = a1.x; f[5] = a1.y; f[6] = a1.z; f[7] = a1.w;
        } else {
#pragma unroll
            for (int j = 0; j < 8; ++j) f[j] = 0.f;
        }
        short8 h, l;
#pragma unroll
        for (int j = 0; j < 8; ++j) {
            unsigned short hh = bf16_hi(f[j]);
            h[j] = (short)hh;
            l[j] = (short)bf16_hi(f[j] - bf16_f(hh));
        }
        ah[ks] = h;
        al[ks] = l;
    }

#pragma unroll
    for (int nt = 0; nt < 8; ++nt) {
        f32x4 acc = {0.f, 0.f, 0.f, 0.f};
#pragma unroll
        for (int ks = 0; ks < 4; ++ks) {
            size_t off = ((size_t)(nt * 4 + ks) * 64 + lane) * 8;
            short8 bh = *(const short8*)(wfh + off);
            short8 bl = *(const short8*)(wfl + off);
            acc = __builtin_amdgcn_mfma_f32_16x16x32_bf16(ah[ks], bh, acc, 0, 0, 0);
            acc = __builtin_amdgcn_mfma_f32_16x16x32_bf16(al[ks], bh, acc, 0, 0, 0);
            acc = __builtin_amdgcn_mfma_f32_16x16x32_bf16(ah[ks], bl, acc, 0, 0, 0);
        }
        float bv = bias[nt * 16 + m];
#pragma unroll
        for (int r = 0; r < 4; ++r) {
            int rr = m0 + quad * 4 + r;  // C/D: col=lane&15, row=quad*4+reg
            if (rr < N) {
                float o = acc[r] + bv;
                if (relu_out) o = o > 0.f ? o : 0.f;
                C[(size_t)rr * ND + nt * 16 + m] = o;
            }
        }
    }
}

extern "C" void kernel_launch(void* const* d_in, const int* in_sizes, int n_in,
                              void* d_out, int out_size, void* d_ws, size_t ws_size,
                              hipStream_t stream) {
    const float* x = (const float*)d_in[0];
    const int* ei = (const int*)d_in[1];  // int64 in reference -> int32 from harness
    const float* ea = (const float*)d_in[2];
    const float* w1_0 = (const float*)d_in[3];
    const float* b1_0 = (const float*)d_in[4];
    const float* w2_0 = (const float*)d_in[5];
    const float* b2_0 = (const float*)d_in[6];
    const float* we_0 = (const float*)d_in[7];
    const float* be_0 = (const float*)d_in[8];
    const float* w1_1 = (const float*)d_in[9];
    const float* b1_1 = (const float*)d_in[10];
    const float* w2_1 = (const float*)d_in[11];
    const float* b2_1 = (const float*)d_in[12];
    const float* we_1 = (const float*)d_in[13];
    const float* be_1 = (const float*)d_in[14];
    const float* fc1_w = (const float*)d_in[15];
    const float* fc1_b = (const float*)d_in[16];
    const float* fc2_w = (const float*)d_in[17];
    const float* fc2_b = (const float*)d_in[18];

    int N = in_sizes[0] / ND;
    int E = in_sizes[2] / ED;

    float* bufA = (float*)d_ws;
    int* counts = (int*)(bufA + (size_t)N * ND);
    int* row_start = counts + N;
    int* woff = row_start + (N + 1);
    int4* pack = (int4*)((((uintptr_t)(woff + N)) + 15) & ~(uintptr_t)15);
    unsigned short* wfh = (unsigned short*)(pack + E);
    unsigned short* wfl = wfh + 6 * 16384;
    unsigned short* weh = wfl + 6 * 16384;  // 2 * 4096
    float* out = (float*)d_out;

    // ---- CSR build + weight prep ----
    zero_kernel<<<(N + 255) / 256, 256, 0, stream>>>(counts, N);
    hist_kernel<<<(E + 255) / 256, 256, 0, stream>>>(ei, counts, E);
    scan_kernel<<<1, 1024, 0, stream>>>(counts, row_start, woff, N);
    scatter_kernel<<<(E + 255) / 256, 256, 0, stream>>>(ei, woff, pack, E);
    wprep_kernel<<<dim3(8, 6), 256, 0, stream>>>(w1_0, w2_0, w1_1, w2_1, fc1_w, fc2_w,
                                                 wfh, wfl);
    wprep_we<<<dim3(2, 2), 256, 0, stream>>>(we_0, we_1, weh);

    const int NW = 4096;  // agg waves (1024 blocks)
    int gg = ((N + 15) / 16 + 3) / 4;  // gemm blocks (4 waves x 16 rows)

    // ---- layer 0 ----
    agg_mfma<<<NW / 4, 256, 0, stream>>>(x, ea, weh, be_0, row_start, pack, bufA, N, NW);
    gemm_mfma<<<gg, 256, 0, stream>>>(bufA, wfh + 0 * 16384, wfl + 0 * 16384, b1_0, out, N, 1);
    gemm_mfma<<<gg, 256, 0, stream>>>(out, wfh + 1 * 16384, wfl + 1 * 16384, b2_0, bufA, N, 1);

    // ---- layer 1 ----
    agg_mfma<<<NW / 4, 256, 0, stream>>>(bufA, ea, weh + 4096, be_1, row_start, pack, out, N, NW);
    gemm_mfma<<<gg, 256, 0, stream>>>(out, wfh + 2 * 16384, wfl + 2 * 16384, b1_1, bufA, N, 1);
    gemm_mfma<<<gg, 256, 0, stream>>>(bufA, wfh + 3 * 16384, wfl + 3 * 16384, b2_1, out, N, 1);

    // ---- head ----
    gemm_mfma<<<gg, 256, 0, stream>>>(out, wfh + 4 * 16384, wfl + 4 * 16384, fc1_b, bufA, N, 1);
    gemm_mfma<<<gg, 256, 0, stream>>>(bufA, wfh + 5 * 16384, wfl + 5 * 16384, fc2_b, out, N, 0);
}

// Round 6
// 576.010 us; speedup vs baseline: 2.1131x; 1.1570x over previous
//
#include <hip/hip_runtime.h>
#include <stdint.h>

// ---------------------------------------------------------------------------
// GINEncoder: 2x GINEConv(eps=0, MLP 128->128->128, edge_lin 32->128) + head.
//   1. CSR by dst (hist + scan + scatter), edges packed int4{src, eid, dst, 0}.
//   2. agg_mfma: node-centric MFMA; 16 edges/chunk = one 16x16x32 A-fragment.
//      R6: x[src] gathers hoisted into xv[4][8] regs (one batched wait),
//      per-nt transient acc, __launch_bounds__(256,4) -> ~128 VGPR budget.
//   3. mlp2_mfma: FUSED pair of 128x128 GEMMs (bf16x3 MFMA, fp32 acc):
//      GEMM1 -> bias+relu -> LDS (132-pad) -> re-split -> GEMM2 -> bias(+relu).
//      Saves the 51MB intermediate round-trip per pair; 3 fused calls total.
// edge_index is int64 in the reference but harness passes int32.
// ---------------------------------------------------------------------------

#define ND 128
#define ED 32

typedef __attribute__((ext_vector_type(8))) short short8;
typedef __attribute__((ext_vector_type(4))) float f32x4;

__device__ inline unsigned short bf16_hi(float f) {
    union { float f; unsigned u; } v;
    v.f = f;
    return (unsigned short)(v.u >> 16);  // truncation; residual captured by lo
}
__device__ inline float bf16_f(unsigned short h) {
    union { unsigned u; float f; } v;
    v.u = ((unsigned)h) << 16;
    return v.f;
}

__global__ __launch_bounds__(256) void zero_kernel(int* __restrict__ p, int n) {
    int i = blockIdx.x * blockDim.x + threadIdx.x;
    if (i < n) p[i] = 0;
}

__global__ __launch_bounds__(256) void hist_kernel(const int* __restrict__ ei,
                                                   int* __restrict__ counts, int E) {
    int i = blockIdx.x * blockDim.x + threadIdx.x;
    if (i < E) atomicAdd(&counts[ei[E + i]], 1);
}

__global__ __launch_bounds__(1024) void scan_kernel(const int* __restrict__ counts,
                                                    int* __restrict__ row_start,
                                                    int* __restrict__ woff, int N) {
    __shared__ int sums[1024];
    int t = threadIdx.x;
    int chunk = (N + 1023) >> 10;
    int lo = min(t * chunk, N);
    int hi = min(lo + chunk, N);
    int s = 0;
    for (int i = lo; i < hi; ++i) s += counts[i];
    sums[t] = s;
    __syncthreads();
    for (int off = 1; off < 1024; off <<= 1) {
        int v = (t >= off) ? sums[t - off] : 0;
        __syncthreads();
        sums[t] += v;
        __syncthreads();
    }
    int pre = (t == 0) ? 0 : sums[t - 1];
    for (int i = lo; i < hi; ++i) {
        row_start[i] = pre;
        woff[i] = pre;
        pre += counts[i];
    }
    if (t == 1023) row_start[N] = sums[1023];
}

__global__ __launch_bounds__(256) void scatter_kernel(const int* __restrict__ ei,
                                                      int* __restrict__ woff,
                                                      int4* __restrict__ pack, int E) {
    int i = blockIdx.x * blockDim.x + threadIdx.x;
    if (i < E) {
        int d = ei[E + i];
        int p = atomicAdd(&woff[d], 1);
        pack[p] = make_int4(ei[i], i, d, 0);  // {src, eid, dst, pad}
    }
}

// Split 6 weight matrices [128,128] into bf16 hi/lo, MFMA B-fragment order:
// chunk c = nt*4+ks; lane l holds B[k=ks*32+(l>>4)*8+j][n=nt*16+(l&15)], j=0..7.
__global__ __launch_bounds__(256) void wprep_kernel(
    const float* __restrict__ w0, const float* __restrict__ w1,
    const float* __restrict__ w2, const float* __restrict__ w3,
    const float* __restrict__ w4, const float* __restrict__ w5,
    unsigned short* __restrict__ hi, unsigned short* __restrict__ lo) {
    int t = blockIdx.x * blockDim.x + threadIdx.x;  // 0..2047
    const float* W;
    switch (blockIdx.y) {
        case 0: W = w0; break;
        case 1: W = w1; break;
        case 2: W = w2; break;
        case 3: W = w3; break;
        case 4: W = w4; break;
        default: W = w5; break;
    }
    unsigned short* dh = hi + (size_t)blockIdx.y * 16384;
    unsigned short* dl = lo + (size_t)blockIdx.y * 16384;
    int c = t >> 6, l = t & 63;
    int nt = c >> 2, ks = c & 3;
    int n = nt * 16 + (l & 15);
    int kb = ks * 32 + ((l >> 4) << 3);
#pragma unroll
    for (int j = 0; j < 8; ++j) {
        float f = W[(size_t)(kb + j) * ND + n];
        unsigned short h = bf16_hi(f);
        dh[((size_t)c * 64 + l) * 8 + j] = h;
        dl[((size_t)c * 64 + l) * 8 + j] = bf16_hi(f - bf16_f(h));
    }
}

// Prep we [32,128] (2 matrices) into bf16-hi B-fragments: chunk = nt (8);
// lane l holds we[k=(l>>4)*8+j][n=nt*16+(l&15)].
__global__ __launch_bounds__(256) void wprep_we(const float* __restrict__ w0,
                                                const float* __restrict__ w1,
                                                unsigned short* __restrict__ hi) {
    int t = threadIdx.x;
    int c = (blockIdx.x << 2) + (t >> 6);  // nt 0..7
    int l = t & 63;
    const float* W = blockIdx.y ? w1 : w0;
    unsigned short* dh = hi + (size_t)blockIdx.y * 4096;
    int n = c * 16 + (l & 15);
    int kb = (l >> 4) << 3;
#pragma unroll
    for (int j = 0; j < 8; ++j)
        dh[((size_t)c * 64 + l) * 8 + j] = bf16_hi(W[(size_t)(kb + j) * ND + n]);
}

// Node-centric MFMA aggregation.
// h[v] = x[v] + sum_{e: dst=v} relu(x[src_e] + ea_e @ we + be)
__global__ __launch_bounds__(256, 4) void agg_mfma(
    const float* __restrict__ xin, const float* __restrict__ edge_attr,
    const unsigned short* __restrict__ bfh, const float* __restrict__ be,
    const int* __restrict__ row_start, const int4* __restrict__ pack,
    float* __restrict__ hout, int N, int NW) {
    int lane = threadIdx.x & 63;
    int gw = (blockIdx.x * blockDim.x + threadIdx.x) >> 6;
    int m = lane & 15;
    int quad = lane >> 4;

    // we fragments (bf16-hi), held in registers for the whole kernel
    short8 bh[8];
#pragma unroll
    for (int nt = 0; nt < 8; ++nt)
        bh[nt] = *(const short8*)(bfh + ((size_t)nt * 64 + lane) * 8);
    float ber[8];
#pragma unroll
    for (int nt = 0; nt < 8; ++nt) ber[nt] = be[nt * 16 + m];

    for (int v = gw; v < N; v += NW) {
        int beg = row_start[v];
        int end = row_start[v + 1];
        float part[8];
#pragma unroll
        for (int nt = 0; nt < 8; ++nt) part[nt] = 0.f;

        for (int base = beg; base < end; base += 16) {
            int rem = end - base;  // >= 1
            int mm = m < rem ? m : rem - 1;
            int4 pk = pack[base + mm];
            // src indices for my quad's 4 C-rows (edges quad*4+r), from lanes 0..15
            int s[4];
#pragma unroll
            for (int r = 0; r < 4; ++r) s[r] = __shfl(pk.x, quad * 4 + r, 64);

            // ---- batched loads: ea row (2x16B) + 32 x-gathers, one wait ----
            const float4* ar = (const float4*)(edge_attr + (size_t)pk.y * ED + quad * 8);
            float4 a0 = ar[0], a1 = ar[1];
            float xv[4][8];
#pragma unroll
            for (int r = 0; r < 4; ++r) {
                const float* xr = xin + (size_t)s[r] * ND + m;
#pragma unroll
                for (int nt = 0; nt < 8; ++nt) xv[r][nt] = xr[nt * 16];
            }

            // A fragment split hi/lo (exact)
            float af[8] = {a0.x, a0.y, a0.z, a0.w, a1.x, a1.y, a1.z, a1.w};
            short8 ah, al;
#pragma unroll
            for (int j = 0; j < 8; ++j) {
                unsigned short h = bf16_hi(af[j]);
                ah[j] = (short)h;
                al[j] = (short)bf16_hi(af[j] - bf16_f(h));
            }

#pragma unroll
            for (int nt = 0; nt < 8; ++nt) {
                f32x4 a = {0.f, 0.f, 0.f, 0.f};
                a = __builtin_amdgcn_mfma_f32_16x16x32_bf16(ah, bh[nt], a, 0, 0, 0);
                a = __builtin_amdgcn_mfma_f32_16x16x32_bf16(al, bh[nt], a, 0, 0, 0);
#pragma unroll
                for (int r = 0; r < 4; ++r) {
                    float vm = (quad * 4 + r) < rem ? 1.f : 0.f;
                    float msg = xv[r][nt] + a[r] + ber[nt];
                    msg = msg > 0.f ? msg : 0.f;
                    part[nt] = fmaf(msg, vm, part[nt]);
                }
            }
        }
        // reduce over quads (cols live in lanes m, m+16, m+32, m+48)
#pragma unroll
        for (int nt = 0; nt < 8; ++nt) {
            float p = part[nt];
            p += __shfl_xor(p, 16, 64);
            p += __shfl_xor(p, 32, 64);
            part[nt] = p;
        }
        // quad q writes cols of tiles 2q, 2q+1
        float o0 = quad == 0 ? part[0] : quad == 1 ? part[2] : quad == 2 ? part[4] : part[6];
        float o1 = quad == 0 ? part[1] : quad == 1 ? part[3] : quad == 2 ? part[5] : part[7];
        int col0 = quad * 32 + m;
        int col1 = col0 + 16;
        hout[(size_t)v * ND + col0] = xin[(size_t)v * ND + col0] + o0;
        hout[(size_t)v * ND + col1] = xin[(size_t)v * ND + col1] + o1;
    }
}

// Fused pair of GEMMs: C = maybe_relu2( relu(A@W1+b1) @ W2 + b2 ).
// Wave = 16 rows; intermediate goes through a per-wave LDS tile (132-pad rows).
#define LP 132  // padded LDS row stride (floats); 132*4B keeps 16B alignment
__global__ __launch_bounds__(256, 4) void mlp2_mfma(
    const float* __restrict__ A,
    const unsigned short* __restrict__ w1h, const unsigned short* __restrict__ w1l,
    const float* __restrict__ b1,
    const unsigned short* __restrict__ w2h, const unsigned short* __restrict__ w2l,
    const float* __restrict__ b2,
    float* __restrict__ C, int N, int relu2) {
    __shared__ float tile[4][16 * LP];
    int lane = threadIdx.x & 63;
    int wave = threadIdx.x >> 6;
    int gw = blockIdx.x * 4 + wave;
    int m0 = gw * 16;
    if (m0 >= N) return;
    int m = lane & 15;
    int quad = lane >> 4;
    float* T = tile[wave];

    // ---- stage 1: load A rows, split hi/lo ----
    int row = m0 + m;
    bool rok = row < N;
    short8 ah[4], al[4];
#pragma unroll
    for (int ks = 0; ks < 4; ++ks) {
        float f[8];
        if (rok) {
            const float4* p = (const float4*)(A + (size_t)row * ND + ks * 32 + quad * 8);
            float4 a0 = p[0], a1 = p[1];
            f[0] = a0.x; f[1] = a0.y; f[2] = a0.z; f[3] = a0.w;
            f[4] = a1.x; f[5] = a1.y; f[6] = a1.z; f[7] = a1.w;
        } else {
#pragma unroll
            for (int j = 0; j < 8; ++j) f[j] = 0.f;
        }
#pragma unroll
        for (int j = 0; j < 8; ++j) {
            unsigned short hh = bf16_hi(f[j]);
            ah[ks][j] = (short)hh;
            al[ks][j] = (short)bf16_hi(f[j] - bf16_f(hh));
        }
    }

    // GEMM1 -> bias + relu -> LDS tile (C/D layout: col=lane&15, row=quad*4+r)
#pragma unroll
    for (int nt = 0; nt < 8; ++nt) {
        f32x4 acc = {0.f, 0.f, 0.f, 0.f};
#pragma unroll
        for (int ks = 0; ks < 4; ++ks) {
            size_t off = ((size_t)(nt * 4 + ks) * 64 + lane) * 8;
            short8 bh = *(const short8*)(w1h + off);
            short8 bl = *(const short8*)(w1l + off);
            acc = __builtin_amdgcn_mfma_f32_16x16x32_bf16(ah[ks], bh, acc, 0, 0, 0);
            acc = __builtin_amdgcn_mfma_f32_16x16x32_bf16(al[ks], bh, acc, 0, 0, 0);
            acc = __builtin_amdgcn_mfma_f32_16x16x32_bf16(ah[ks], bl, acc, 0, 0, 0);
        }
        float bv = b1[nt * 16 + m];
#pragma unroll
        for (int r = 0; r < 4; ++r) {
            float o = acc[r] + bv;
            o = o > 0.f ? o : 0.f;
            T[(quad * 4 + r) * LP + nt * 16 + m] = o;
        }
    }

    // ---- stage 2: rows from LDS as A-fragments (same wave -> lgkmcnt wait) ----
    short8 ch[4], cl[4];
#pragma unroll
    for (int ks = 0; ks < 4; ++ks) {
        const float4* p = (const float4*)(T + m * LP + ks * 32 + quad * 8);
        float4 a0 = p[0], a1 = p[1];
        float f[8] = {a0.x, a0.y, a0.z, a0.w, a1.x, a1.y, a1.z, a1.w};
#pragma unroll
        for (int j = 0; j < 8; ++j) {
            unsigned short hh = bf16_hi(f[j]);
            ch[ks][j] = (short)hh;
            cl[ks][j] = (short)bf16_hi(f[j] - bf16_f(hh));
        }
    }

#pragma unroll
    for (int nt = 0; nt < 8; ++nt) {
        f32x4 acc = {0.f, 0.f, 0.f, 0.f};
#pragma unroll
        for (int ks = 0; ks < 4; ++ks) {
            size_t off = ((size_t)(nt * 4 + ks) * 64 + lane) * 8;
            short8 bh = *(const short8*)(w2h + off);
            short8 bl = *(const short8*)(w2l + off);
            acc = __builtin_amdgcn_mfma_f32_16x16x32_bf16(ch[ks], bh, acc, 0, 0, 0);
            acc = __builtin_amdgcn_mfma_f32_16x16x32_bf16(cl[ks], bh, acc, 0, 0, 0);
            acc = __builtin_amdgcn_mfma_f32_16x16x32_bf16(ch[ks], bl, acc, 0, 0, 0);
        }
        float bv = b2[nt * 16 + m];
#pragma unroll
        for (int r = 0; r < 4; ++r) {
            int rr = m0 + quad * 4 + r;
            if (rr < N) {
                float o = acc[r] + bv;
                if (relu2) o = o > 0.f ? o : 0.f;
                C[(size_t)rr * ND + nt * 16 + m] = o;
            }
        }
    }
}

extern "C" void kernel_launch(void* const* d_in, const int* in_sizes, int n_in,
                              void* d_out, int out_size, void* d_ws, size_t ws_size,
                              hipStream_t stream) {
    const float* x = (const float*)d_in[0];
    const int* ei = (const int*)d_in[1];  // int64 in reference -> int32 from harness
    const float* ea = (const float*)d_in[2];
    const float* w1_0 = (const float*)d_in[3];
    const float* b1_0 = (const float*)d_in[4];
    const float* w2_0 = (const float*)d_in[5];
    const float* b2_0 = (const float*)d_in[6];
    const float* we_0 = (const float*)d_in[7];
    const float* be_0 = (const float*)d_in[8];
    const float* w1_1 = (const float*)d_in[9];
    const float* b1_1 = (const float*)d_in[10];
    const float* w2_1 = (const float*)d_in[11];
    const float* b2_1 = (const float*)d_in[12];
    const float* we_1 = (const float*)d_in[13];
    const float* be_1 = (const float*)d_in[14];
    const float* fc1_w = (const float*)d_in[15];
    const float* fc1_b = (const float*)d_in[16];
    const float* fc2_w = (const float*)d_in[17];
    const float* fc2_b = (const float*)d_in[18];

    int N = in_sizes[0] / ND;
    int E = in_sizes[2] / ED;

    float* bufA = (float*)d_ws;
    int* counts = (int*)(bufA + (size_t)N * ND);
    int* row_start = counts + N;
    int* woff = row_start + (N + 1);
    int4* pack = (int4*)((((uintptr_t)(woff + N)) + 15) & ~(uintptr_t)15);
    unsigned short* wfh = (unsigned short*)(pack + E);
    unsigned short* wfl = wfh + 6 * 16384;
    unsigned short* weh = wfl + 6 * 16384;  // 2 * 4096
    float* out = (float*)d_out;

    // ---- CSR build + weight prep ----
    zero_kernel<<<(N + 255) / 256, 256, 0, stream>>>(counts, N);
    hist_kernel<<<(E + 255) / 256, 256, 0, stream>>>(ei, counts, E);
    scan_kernel<<<1, 1024, 0, stream>>>(counts, row_start, woff, N);
    scatter_kernel<<<(E + 255) / 256, 256, 0, stream>>>(ei, woff, pack, E);
    wprep_kernel<<<dim3(8, 6), 256, 0, stream>>>(w1_0, w2_0, w1_1, w2_1, fc1_w, fc2_w,
                                                 wfh, wfl);
    wprep_we<<<dim3(2, 2), 256, 0, stream>>>(we_0, we_1, weh);

    const int NW = 4096;  // agg waves (1024 blocks = 4 blocks/CU at 4 waves/SIMD)
    int gg = ((N + 15) / 16 + 3) / 4;  // fused-MLP blocks (4 waves x 16 rows)

    // ---- layer 0 ----  agg0: x -> out; mlp0: out -> bufA
    agg_mfma<<<NW / 4, 256, 0, stream>>>(x, ea, weh, be_0, row_start, pack, out, N, NW);
    mlp2_mfma<<<gg, 256, 0, stream>>>(out, wfh + 0 * 16384, wfl + 0 * 16384, b1_0,
                                      wfh + 1 * 16384, wfl + 1 * 16384, b2_0, bufA, N, 1);

    // ---- layer 1 ----  agg1: bufA -> out; mlp1: out -> bufA
    agg_mfma<<<NW / 4, 256, 0, stream>>>(bufA, ea, weh + 4096, be_1, row_start, pack, out,
                                         N, NW);
    mlp2_mfma<<<gg, 256, 0, stream>>>(out, wfh + 2 * 16384, wfl + 2 * 16384, b1_1,
                                      wfh + 3 * 16384, wfl + 3 * 16384, b2_1, bufA, N, 1);

    // ---- head ----  bufA -> out (final)
    mlp2_mfma<<<gg, 256, 0, stream>>>(bufA, wfh + 4 * 16384, wfl + 4 * 16384, fc1_b,
                                      wfh + 5 * 16384, wfl + 5 * 16384, fc2_b, out, N, 0);
}

// Round 7
// 470.762 us; speedup vs baseline: 2.5855x; 1.2236x over previous
//
#include <hip/hip_runtime.h>
#include <stdint.h>

// ---------------------------------------------------------------------------
// GINEncoder: 2x GINEConv(eps=0, MLP 128->128->128, edge_lin 32->128) + head.
//   1. CSR by dst: hist + TWO-LEVEL parallel scan (bsum/scan_bsums/expand) +
//      scatter; edges packed int4{src, eid, dst, 0}.
//      (R7: old single-block scan_kernel was 110us = 19% of runtime.)
//   2. agg_mfma: node-centric MFMA; 16 edges/chunk = one 16x16x32 A-fragment;
//      x[src] gathers batched into regs; __launch_bounds__(256,4).
//   3. mlp2_mfma: fused GEMM pairs (bf16x3 MFMA, fp32 acc) via per-wave LDS.
// edge_index is int64 in the reference but harness passes int32.
// ---------------------------------------------------------------------------

#define ND 128
#define ED 32

typedef __attribute__((ext_vector_type(8))) short short8;
typedef __attribute__((ext_vector_type(4))) float f32x4;

__device__ inline unsigned short bf16_hi(float f) {
    union { float f; unsigned u; } v;
    v.f = f;
    return (unsigned short)(v.u >> 16);  // truncation; residual captured by lo
}
__device__ inline float bf16_f(unsigned short h) {
    union { unsigned u; float f; } v;
    v.u = ((unsigned)h) << 16;
    return v.f;
}

__global__ __launch_bounds__(256) void zero_kernel(int* __restrict__ p, int n) {
    int i = blockIdx.x * blockDim.x + threadIdx.x;
    if (i < n) p[i] = 0;
}

__global__ __launch_bounds__(256) void hist_kernel(const int* __restrict__ ei,
                                                   int* __restrict__ counts, int E) {
    int i = blockIdx.x * blockDim.x + threadIdx.x;
    if (i < E) atomicAdd(&counts[ei[E + i]], 1);
}

// ---- two-level parallel scan over counts[N] ----
__global__ __launch_bounds__(256) void bsum_kernel(const int* __restrict__ counts,
                                                   int* __restrict__ bsum, int N) {
    __shared__ int s[256];
    int t = threadIdx.x;
    int i = blockIdx.x * 256 + t;
    s[t] = (i < N) ? counts[i] : 0;
    __syncthreads();
#pragma unroll
    for (int off = 128; off > 0; off >>= 1) {
        if (t < off) s[t] += s[t + off];
        __syncthreads();
    }
    if (t == 0) bsum[blockIdx.x] = s[0];
}

__global__ __launch_bounds__(256) void scan_bsums(const int* __restrict__ bsum,
                                                  int* __restrict__ bofs,
                                                  int* __restrict__ row_start_N, int NB) {
    __shared__ int s[256];
    int t = threadIdx.x;
    int chunk = (NB + 255) >> 8;
    int lo = min(t * chunk, NB);
    int hi = min(lo + chunk, NB);
    int sum = 0;
    for (int i = lo; i < hi; ++i) sum += bsum[i];
    s[t] = sum;
    __syncthreads();
    for (int off = 1; off < 256; off <<= 1) {
        int v = (t >= off) ? s[t - off] : 0;
        __syncthreads();
        s[t] += v;
        __syncthreads();
    }
    int pre = (t == 0) ? 0 : s[t - 1];
    for (int i = lo; i < hi; ++i) {
        bofs[i] = pre;
        pre += bsum[i];
    }
    if (t == 255) *row_start_N = s[255];
}

__global__ __launch_bounds__(256) void expand_kernel(const int* __restrict__ counts,
                                                     const int* __restrict__ bofs,
                                                     int* __restrict__ row_start,
                                                     int* __restrict__ woff, int N) {
    __shared__ int s[256];
    int t = threadIdx.x;
    int i = blockIdx.x * 256 + t;
    int c = (i < N) ? counts[i] : 0;
    s[t] = c;
    __syncthreads();
    for (int off = 1; off < 256; off <<= 1) {
        int v = (t >= off) ? s[t - off] : 0;
        __syncthreads();
        s[t] += v;
        __syncthreads();
    }
    if (i < N) {
        int pre = bofs[blockIdx.x] + s[t] - c;  // exclusive
        row_start[i] = pre;
        woff[i] = pre;
    }
}

__global__ __launch_bounds__(256) void scatter_kernel(const int* __restrict__ ei,
                                                      int* __restrict__ woff,
                                                      int4* __restrict__ pack, int E) {
    int i = blockIdx.x * blockDim.x + threadIdx.x;
    if (i < E) {
        int d = ei[E + i];
        int p = atomicAdd(&woff[d], 1);
        pack[p] = make_int4(ei[i], i, d, 0);  // {src, eid, dst, pad}
    }
}

// Split 6 weight matrices [128,128] into bf16 hi/lo, MFMA B-fragment order:
// chunk c = nt*4+ks; lane l holds B[k=ks*32+(l>>4)*8+j][n=nt*16+(l&15)], j=0..7.
__global__ __launch_bounds__(256) void wprep_kernel(
    const float* __restrict__ w0, const float* __restrict__ w1,
    const float* __restrict__ w2, const float* __restrict__ w3,
    const float* __restrict__ w4, const float* __restrict__ w5,
    unsigned short* __restrict__ hi, unsigned short* __restrict__ lo) {
    int t = blockIdx.x * blockDim.x + threadIdx.x;  // 0..2047
    const float* W;
    switch (blockIdx.y) {
        case 0: W = w0; break;
        case 1: W = w1; break;
        case 2: W = w2; break;
        case 3: W = w3; break;
        case 4: W = w4; break;
        default: W = w5; break;
    }
    unsigned short* dh = hi + (size_t)blockIdx.y * 16384;
    unsigned short* dl = lo + (size_t)blockIdx.y * 16384;
    int c = t >> 6, l = t & 63;
    int nt = c >> 2, ks = c & 3;
    int n = nt * 16 + (l & 15);
    int kb = ks * 32 + ((l >> 4) << 3);
#pragma unroll
    for (int j = 0; j < 8; ++j) {
        float f = W[(size_t)(kb + j) * ND + n];
        unsigned short h = bf16_hi(f);
        dh[((size_t)c * 64 + l) * 8 + j] = h;
        dl[((size_t)c * 64 + l) * 8 + j] = bf16_hi(f - bf16_f(h));
    }
}

// Prep we [32,128] (2 matrices) into bf16-hi B-fragments: chunk = nt (8);
// lane l holds we[k=(l>>4)*8+j][n=nt*16+(l&15)].
__global__ __launch_bounds__(256) void wprep_we(const float* __restrict__ w0,
                                                const float* __restrict__ w1,
                                                unsigned short* __restrict__ hi) {
    int t = threadIdx.x;
    int c = (blockIdx.x << 2) + (t >> 6);  // nt 0..7
    int l = t & 63;
    const float* W = blockIdx.y ? w1 : w0;
    unsigned short* dh = hi + (size_t)blockIdx.y * 4096;
    int n = c * 16 + (l & 15);
    int kb = (l >> 4) << 3;
#pragma unroll
    for (int j = 0; j < 8; ++j)
        dh[((size_t)c * 64 + l) * 8 + j] = bf16_hi(W[(size_t)(kb + j) * ND + n]);
}

// Node-centric MFMA aggregation.
// h[v] = x[v] + sum_{e: dst=v} relu(x[src_e] + ea_e @ we + be)
__global__ __launch_bounds__(256, 4) void agg_mfma(
    const float* __restrict__ xin, const float* __restrict__ edge_attr,
    const unsigned short* __restrict__ bfh, const float* __restrict__ be,
    const int* __restrict__ row_start, const int4* __restrict__ pack,
    float* __restrict__ hout, int N, int NW) {
    int lane = threadIdx.x & 63;
    int gw = (blockIdx.x * blockDim.x + threadIdx.x) >> 6;
    int m = lane & 15;
    int quad = lane >> 4;

    // we fragments (bf16-hi), held in registers for the whole kernel
    short8 bh[8];
#pragma unroll
    for (int nt = 0; nt < 8; ++nt)
        bh[nt] = *(const short8*)(bfh + ((size_t)nt * 64 + lane) * 8);
    float ber[8];
#pragma unroll
    for (int nt = 0; nt < 8; ++nt) ber[nt] = be[nt * 16 + m];

    for (int v = gw; v < N; v += NW) {
        int beg = row_start[v];
        int end = row_start[v + 1];
        float part[8];
#pragma unroll
        for (int nt = 0; nt < 8; ++nt) part[nt] = 0.f;

        for (int base = beg; base < end; base += 16) {
            int rem = end - base;  // >= 1
            int mm = m < rem ? m : rem - 1;
            int4 pk = pack[base + mm];
            // src indices for my quad's 4 C-rows (edges quad*4+r), from lanes 0..15
            int s[4];
#pragma unroll
            for (int r = 0; r < 4; ++r) s[r] = __shfl(pk.x, quad * 4 + r, 64);

            // ---- batched loads: ea row (2x16B) + 32 x-gathers, one wait ----
            const float4* ar = (const float4*)(edge_attr + (size_t)pk.y * ED + quad * 8);
            float4 a0 = ar[0], a1 = ar[1];
            float xv[4][8];
#pragma unroll
            for (int r = 0; r < 4; ++r) {
                const float* xr = xin + (size_t)s[r] * ND + m;
#pragma unroll
                for (int nt = 0; nt < 8; ++nt) xv[r][nt] = xr[nt * 16];
            }

            // A fragment split hi/lo (exact)
            float af[8] = {a0.x, a0.y, a0.z, a0.w, a1.x, a1.y, a1.z, a1.w};
            short8 ah, al;
#pragma unroll
            for (int j = 0; j < 8; ++j) {
                unsigned short h = bf16_hi(af[j]);
                ah[j] = (short)h;
                al[j] = (short)bf16_hi(af[j] - bf16_f(h));
            }

#pragma unroll
            for (int nt = 0; nt < 8; ++nt) {
                f32x4 a = {0.f, 0.f, 0.f, 0.f};
                a = __builtin_amdgcn_mfma_f32_16x16x32_bf16(ah, bh[nt], a, 0, 0, 0);
                a = __builtin_amdgcn_mfma_f32_16x16x32_bf16(al, bh[nt], a, 0, 0, 0);
#pragma unroll
                for (int r = 0; r < 4; ++r) {
                    float vm = (quad * 4 + r) < rem ? 1.f : 0.f;
                    float msg = xv[r][nt] + a[r] + ber[nt];
                    msg = msg > 0.f ? msg : 0.f;
                    part[nt] = fmaf(msg, vm, part[nt]);
                }
            }
        }
        // reduce over quads (cols live in lanes m, m+16, m+32, m+48)
#pragma unroll
        for (int nt = 0; nt < 8; ++nt) {
            float p = part[nt];
            p += __shfl_xor(p, 16, 64);
            p += __shfl_xor(p, 32, 64);
            part[nt] = p;
        }
        // quad q writes cols of tiles 2q, 2q+1
        float o0 = quad == 0 ? part[0] : quad == 1 ? part[2] : quad == 2 ? part[4] : part[6];
        float o1 = quad == 0 ? part[1] : quad == 1 ? part[3] : quad == 2 ? part[5] : part[7];
        int col0 = quad * 32 + m;
        int col1 = col0 + 16;
        hout[(size_t)v * ND + col0] = xin[(size_t)v * ND + col0] + o0;
        hout[(size_t)v * ND + col1] = xin[(size_t)v * ND + col1] + o1;
    }
}

// Fused pair of GEMMs: C = maybe_relu2( relu(A@W1+b1) @ W2 + b2 ).
// Wave = 16 rows; intermediate goes through a per-wave LDS tile (132-pad rows).
#define LP 132  // padded LDS row stride (floats); 132*4B keeps 16B alignment
__global__ __launch_bounds__(256, 4) void mlp2_mfma(
    const float* __restrict__ A,
    const unsigned short* __restrict__ w1h, const unsigned short* __restrict__ w1l,
    const float* __restrict__ b1,
    const unsigned short* __restrict__ w2h, const unsigned short* __restrict__ w2l,
    const float* __restrict__ b2,
    float* __restrict__ C, int N, int relu2) {
    __shared__ float tile[4][16 * LP];
    int lane = threadIdx.x & 63;
    int wave = threadIdx.x >> 6;
    int gw = blockIdx.x * 4 + wave;
    int m0 = gw * 16;
    if (m0 >= N) return;
    int m = lane & 15;
    int quad = lane >> 4;
    float* T = tile[wave];

    // ---- stage 1: load A rows, split hi/lo ----
    int row = m0 + m;
    bool rok = row < N;
    short8 ah[4], al[4];
#pragma unroll
    for (int ks = 0; ks < 4; ++ks) {
        float f[8];
        if (rok) {
            const float4* p = (const float4*)(A + (size_t)row * ND + ks * 32 + quad * 8);
            float4 a0 = p[0], a1 = p[1];
            f[0] = a0.x; f[1] = a0.y; f[2] = a0.z; f[3] = a0.w;
            f[4] = a1.x; f[5] = a1.y; f[6] = a1.z; f[7] = a1.w;
        } else {
#pragma unroll
            for (int j = 0; j < 8; ++j) f[j] = 0.f;
        }
#pragma unroll
        for (int j = 0; j < 8; ++j) {
            unsigned short hh = bf16_hi(f[j]);
            ah[ks][j] = (short)hh;
            al[ks][j] = (short)bf16_hi(f[j] - bf16_f(hh));
        }
    }

    // GEMM1 -> bias + relu -> LDS tile (C/D layout: col=lane&15, row=quad*4+r)
#pragma unroll
    for (int nt = 0; nt < 8; ++nt) {
        f32x4 acc = {0.f, 0.f, 0.f, 0.f};
#pragma unroll
        for (int ks = 0; ks < 4; ++ks) {
            size_t off = ((size_t)(nt * 4 + ks) * 64 + lane) * 8;
            short8 bh = *(const short8*)(w1h + off);
            short8 bl = *(const short8*)(w1l + off);
            acc = __builtin_amdgcn_mfma_f32_16x16x32_bf16(ah[ks], bh, acc, 0, 0, 0);
            acc = __builtin_amdgcn_mfma_f32_16x16x32_bf16(al[ks], bh, acc, 0, 0, 0);
            acc = __builtin_amdgcn_mfma_f32_16x16x32_bf16(ah[ks], bl, acc, 0, 0, 0);
        }
        float bv = b1[nt * 16 + m];
#pragma unroll
        for (int r = 0; r < 4; ++r) {
            float o = acc[r] + bv;
            o = o > 0.f ? o : 0.f;
            T[(quad * 4 + r) * LP + nt * 16 + m] = o;
        }
    }

    // ---- stage 2: rows from LDS as A-fragments (same wave -> lgkmcnt wait) ----
    short8 ch[4], cl[4];
#pragma unroll
    for (int ks = 0; ks < 4; ++ks) {
        const float4* p = (const float4*)(T + m * LP + ks * 32 + quad * 8);
        float4 a0 = p[0], a1 = p[1];
        float f[8] = {a0.x, a0.y, a0.z, a0.w, a1.x, a1.y, a1.z, a1.w};
#pragma unroll
        for (int j = 0; j < 8; ++j) {
            unsigned short hh = bf16_hi(f[j]);
            ch[ks][j] = (short)hh;
            cl[ks][j] = (short)bf16_hi(f[j] - bf16_f(hh));
        }
    }

#pragma unroll
    for (int nt = 0; nt < 8; ++nt) {
        f32x4 acc = {0.f, 0.f, 0.f, 0.f};
#pragma unroll
        for (int ks = 0; ks < 4; ++ks) {
            size_t off = ((size_t)(nt * 4 + ks) * 64 + lane) * 8;
            short8 bh = *(const short8*)(w2h + off);
            short8 bl = *(const short8*)(w2l + off);
            acc = __builtin_amdgcn_mfma_f32_16x16x32_bf16(ch[ks], bh, acc, 0, 0, 0);
            acc = __builtin_amdgcn_mfma_f32_16x16x32_bf16(cl[ks], bh, acc, 0, 0, 0);
            acc = __builtin_amdgcn_mfma_f32_16x16x32_bf16(ch[ks], bl, acc, 0, 0, 0);
        }
        float bv = b2[nt * 16 + m];
#pragma unroll
        for (int r = 0; r < 4; ++r) {
            int rr = m0 + quad * 4 + r;
            if (rr < N) {
                float o = acc[r] + bv;
                if (relu2) o = o > 0.f ? o : 0.f;
                C[(size_t)rr * ND + nt * 16 + m] = o;
            }
        }
    }
}

extern "C" void kernel_launch(void* const* d_in, const int* in_sizes, int n_in,
                              void* d_out, int out_size, void* d_ws, size_t ws_size,
                              hipStream_t stream) {
    const float* x = (const float*)d_in[0];
    const int* ei = (const int*)d_in[1];  // int64 in reference -> int32 from harness
    const float* ea = (const float*)d_in[2];
    const float* w1_0 = (const float*)d_in[3];
    const float* b1_0 = (const float*)d_in[4];
    const float* w2_0 = (const float*)d_in[5];
    const float* b2_0 = (const float*)d_in[6];
    const float* we_0 = (const float*)d_in[7];
    const float* be_0 = (const float*)d_in[8];
    const float* w1_1 = (const float*)d_in[9];
    const float* b1_1 = (const float*)d_in[10];
    const float* w2_1 = (const float*)d_in[11];
    const float* b2_1 = (const float*)d_in[12];
    const float* we_1 = (const float*)d_in[13];
    const float* be_1 = (const float*)d_in[14];
    const float* fc1_w = (const float*)d_in[15];
    const float* fc1_b = (const float*)d_in[16];
    const float* fc2_w = (const float*)d_in[17];
    const float* fc2_b = (const float*)d_in[18];

    int N = in_sizes[0] / ND;
    int E = in_sizes[2] / ED;
    int NB = (N + 255) / 256;

    float* bufA = (float*)d_ws;
    int* counts = (int*)(bufA + (size_t)N * ND);
    int* row_start = counts + N;
    int* woff = row_start + (N + 1);
    int* bsum = woff + N;
    int* bofs = bsum + NB;
    int4* pack = (int4*)((((uintptr_t)(bofs + NB)) + 15) & ~(uintptr_t)15);
    unsigned short* wfh = (unsigned short*)(pack + E);
    unsigned short* wfl = wfh + 6 * 16384;
    unsigned short* weh = wfl + 6 * 16384;  // 2 * 4096
    float* out = (float*)d_out;

    // ---- CSR build (two-level parallel scan) + weight prep ----
    zero_kernel<<<(N + 255) / 256, 256, 0, stream>>>(counts, N);
    hist_kernel<<<(E + 255) / 256, 256, 0, stream>>>(ei, counts, E);
    bsum_kernel<<<NB, 256, 0, stream>>>(counts, bsum, N);
    scan_bsums<<<1, 256, 0, stream>>>(bsum, bofs, row_start + N, NB);
    expand_kernel<<<NB, 256, 0, stream>>>(counts, bofs, row_start, woff, N);
    scatter_kernel<<<(E + 255) / 256, 256, 0, stream>>>(ei, woff, pack, E);
    wprep_kernel<<<dim3(8, 6), 256, 0, stream>>>(w1_0, w2_0, w1_1, w2_1, fc1_w, fc2_w,
                                                 wfh, wfl);
    wprep_we<<<dim3(2, 2), 256, 0, stream>>>(we_0, we_1, weh);

    const int NW = 4096;  // agg waves (1024 blocks = 4 blocks/CU at 4 waves/SIMD)
    int gg = ((N + 15) / 16 + 3) / 4;  // fused-MLP blocks (4 waves x 16 rows)

    // ---- layer 0 ----  agg0: x -> out; mlp0: out -> bufA
    agg_mfma<<<NW / 4, 256, 0, stream>>>(x, ea, weh, be_0, row_start, pack, out, N, NW);
    mlp2_mfma<<<gg, 256, 0, stream>>>(out, wfh + 0 * 16384, wfl + 0 * 16384, b1_0,
                                      wfh + 1 * 16384, wfl + 1 * 16384, b2_0, bufA, N, 1);

    // ---- layer 1 ----  agg1: bufA -> out; mlp1: out -> bufA
    agg_mfma<<<NW / 4, 256, 0, stream>>>(bufA, ea, weh + 4096, be_1, row_start, pack, out,
                                         N, NW);
    mlp2_mfma<<<gg, 256, 0, stream>>>(out, wfh + 2 * 16384, wfl + 2 * 16384, b1_1,
                                      wfh + 3 * 16384, wfl + 3 * 16384, b2_1, bufA, N, 1);

    // ---- head ----  bufA -> out (final)
    mlp2_mfma<<<gg, 256, 0, stream>>>(bufA, wfh + 4 * 16384, wfl + 4 * 16384, fc1_b,
                                      wfh + 5 * 16384, wfl + 5 * 16384, fc2_b, out, N, 0);
}